// Round 11
// baseline (724.337 us; speedup 1.0000x reference)
//
#include <hip/hip_runtime.h>
#include <stdint.h>

#define B_ 64
#define S_ 512
#define H_ 1024
#define M_ (B_*S_)   // 32768 rows of the big GEMM

typedef __bf16 bf16x8 __attribute__((ext_vector_type(8)));
typedef __bf16 bf16x4 __attribute__((ext_vector_type(4)));
typedef float  f32x4  __attribute__((ext_vector_type(4)));

typedef const __attribute__((address_space(1))) uint32_t glb_u32;
typedef __attribute__((address_space(3))) uint32_t lds_u32;

__device__ __forceinline__ float tanh_fast(float x) {
  float e = __expf(2.0f * x);
  return 1.0f - 2.0f * __builtin_amdgcn_rcpf(e + 1.0f);
}

// ---------------------------------------------------------------------------
// K0: fp32 -> bf16 streaming convert
// ---------------------------------------------------------------------------
__global__ void convert_bf16_kernel(const float* __restrict__ in,
                                    __bf16* __restrict__ out, int n8) {
  int i = blockIdx.x * 256 + threadIdx.x;
  const int stride = gridDim.x * 256;
  for (; i < n8; i += stride) {
    const float4 a = ((const float4*)in)[2*i];
    const float4 b = ((const float4*)in)[2*i+1];
    bf16x8 v;
    v[0]=(__bf16)a.x; v[1]=(__bf16)a.y; v[2]=(__bf16)a.z; v[3]=(__bf16)a.w;
    v[4]=(__bf16)b.x; v[5]=(__bf16)b.y; v[6]=(__bf16)b.z; v[7]=(__bf16)b.w;
    ((bf16x8*)out)[i] = v;
  }
}

// ---------------------------------------------------------------------------
// K1: row_bias[b][o] = last_dehy[b]·W_de[o] + b_de[o]+b_en[o]+b_cv[o]
// ---------------------------------------------------------------------------
__global__ void rowbias_kernel(const float* __restrict__ ldh,
                               const float* __restrict__ Wde,
                               const float* __restrict__ ben,
                               const float* __restrict__ bde,
                               const float* __restrict__ bcv,
                               float* __restrict__ row_bias) {
  const int b    = blockIdx.x;
  const int og   = blockIdx.y;
  const int wave = threadIdx.x >> 6;
  const int lane = threadIdx.x & 63;

  float4 l4[4];
#pragma unroll
  for (int i = 0; i < 4; ++i)
    l4[i] = *(const float4*)&ldh[b*H_ + i*256 + lane*4];

  for (int oi = 0; oi < 16; ++oi) {
    const int o = og*64 + wave*16 + oi;
    const float* wr = &Wde[(size_t)o * H_];
    float s = 0.f;
#pragma unroll
    for (int i = 0; i < 4; ++i) {
      float4 w4 = *(const float4*)&wr[i*256 + lane*4];
      s += w4.x*l4[i].x + w4.y*l4[i].y + w4.z*l4[i].z + w4.w*l4[i].w;
    }
#pragma unroll
    for (int off = 32; off; off >>= 1) s += __shfl_xor(s, off);
    if (lane == 0) row_bias[b*H_ + o] = s + bde[o] + ben[o] + bcv[o];
  }
}

// ---------------------------------------------------------------------------
// K2: 256x256 bf16 GEMM, single-buffer / 2-blocks-per-CU (m114 cross-block
// overlap regime). Per K-tile: bar -> 8x gload_lds -> vmcnt(0) -> bar ->
// {24 ds_read + 4x16-MFMA clusters, setprio}. LDS 68 KB -> 2 blocks/CU,
// 4 waves/SIMD; the stage-drain stall of one block hides under the other
// block's MFMA phase. Swizzle/addressing/epilogue identical to R10.
// ---------------------------------------------------------------------------
__global__ __launch_bounds__(512, 4)
void gemmsb_kernel(const __bf16* __restrict__ A,
                   const __bf16* __restrict__ Bt,
                   const float* __restrict__ row_bias,
                   const float* __restrict__ past_attn,
                   const float* __restrict__ Wcv,
                   const float* __restrict__ Wout,
                   float* __restrict__ logits_part) {
  __shared__ __bf16 L[4][8192];      // [half][elems] 64 KB single buffer
  __shared__ float  rowsum[256][4];  // 4 KB

  // XCD-bijective swizzle: 4 n-tiles of one m-tile adjacent on one XCD.
  const int bid  = blockIdx.x;               // 512 blocks, 512 % 8 == 0
  const int tile = (bid & 7) * 64 + (bid >> 3);
  const int mt = tile >> 2, nt4 = tile & 3;
  const int m0 = mt * 256, n0 = nt4 * 256;

  const int tid  = threadIdx.x;
  const int w    = tid >> 6, lane = tid & 63;
  const int wm   = w >> 2,   wn   = w & 3;
  const int fr   = lane & 15, fq = lane >> 4;

  // fragment-read addressing (row&7 == fr&7 for all regions):
  const int o0 = fr*128 + ((fq ^ (fr & 7)) * 16);
  const int o1 = fr*128 + (((4 + fq) ^ (fr & 7)) * 16);
  const char* a0p = (const char*)L + wm*16384;
  const char* b0p = (const char*)L + 32768 + (wn >> 1)*16384 + (wn & 1)*8192;

#define LDA(mi, kk) (*(const bf16x8*)(a0p + ((kk) ? o1 : o0) + (mi)*2048))
#define LDB(ni, kk) (*(const bf16x8*)(b0p + ((kk) ? o1 : o0) + (ni)*2048))

  // staging: per-lane global src (inverse-swizzled), wave-uniform LDS dst
  const int srow = w*8 + (lane >> 3);
  const int sc16 = (lane & 7) ^ ((lane >> 3) & 7);
  const __bf16* gA = A  + (size_t)(m0 + srow)*H_ + sc16*8;
  const __bf16* gB = Bt + (size_t)(n0 + srow)*H_ + sc16*8;
  const __bf16 *paA0 = gA, *paA1 = gA + (size_t)64*H_,
               *paA2 = gA + (size_t)128*H_, *paA3 = gA + (size_t)192*H_;
  const __bf16 *paB0 = gB, *paB1 = gB + (size_t)64*H_,
               *paB2 = gB + (size_t)128*H_, *paB3 = gB + (size_t)192*H_;
  char* ldsw = (char*)L + w*1024;

#define STG_ALL do { \
    __builtin_amdgcn_global_load_lds((glb_u32*)paA0, (lds_u32*)(ldsw        ), 16, 0, 0); \
    __builtin_amdgcn_global_load_lds((glb_u32*)paA1, (lds_u32*)(ldsw +  8192), 16, 0, 0); \
    __builtin_amdgcn_global_load_lds((glb_u32*)paA2, (lds_u32*)(ldsw + 16384), 16, 0, 0); \
    __builtin_amdgcn_global_load_lds((glb_u32*)paA3, (lds_u32*)(ldsw + 24576), 16, 0, 0); \
    __builtin_amdgcn_global_load_lds((glb_u32*)paB0, (lds_u32*)(ldsw + 32768), 16, 0, 0); \
    __builtin_amdgcn_global_load_lds((glb_u32*)paB1, (lds_u32*)(ldsw + 40960), 16, 0, 0); \
    __builtin_amdgcn_global_load_lds((glb_u32*)paB2, (lds_u32*)(ldsw + 49152), 16, 0, 0); \
    __builtin_amdgcn_global_load_lds((glb_u32*)paB3, (lds_u32*)(ldsw + 57344), 16, 0, 0); \
    paA0 += 64; paA1 += 64; paA2 += 64; paA3 += 64;                                       \
    paB0 += 64; paB1 += 64; paB2 += 64; paB3 += 64; } while (0)

  f32x4 acc[8][4] = {};
  bf16x8 a0f[4], a1f[4], a2f[4], a3f[4], b0f[4], b1f[4];

#define MF16(AF, BF, BASE) { _Pragma("unroll") for (int mi = 0; mi < 4; ++mi) \
                             _Pragma("unroll") for (int ni = 0; ni < 4; ++ni) \
                               acc[(BASE)+mi][ni] = __builtin_amdgcn_mfma_f32_16x16x32_bf16((AF)[mi], (BF)[ni], acc[(BASE)+mi][ni], 0, 0, 0); }
#define BAR   __builtin_amdgcn_s_barrier()
#define PRIO1 __builtin_amdgcn_s_setprio(1)
#define PRIO0 __builtin_amdgcn_s_setprio(0)
#define VM0   asm volatile("s_waitcnt vmcnt(0)" ::: "memory")

#pragma unroll 1
  for (int kt = 0; kt < 16; ++kt) {
    BAR;            // all waves done reading previous tile's LDS
    STG_ALL;        // 8 direct-to-LDS loads for this tile
    VM0;            // this wave's loads landed
    BAR;            // every wave's loads landed -> tile resident

    { _Pragma("unroll") for (int ni = 0; ni < 4; ++ni) b0f[ni] = LDB(ni, 0); }
    { _Pragma("unroll") for (int ni = 0; ni < 4; ++ni) b1f[ni] = LDB(ni, 1); }
    { _Pragma("unroll") for (int mi = 0; mi < 4; ++mi) a0f[mi] = LDA(mi, 0); }
    { _Pragma("unroll") for (int mi = 0; mi < 4; ++mi) a1f[mi] = LDA(mi, 1); }
    PRIO1; MF16(a0f, b0f, 0); PRIO0;
    { _Pragma("unroll") for (int mi = 0; mi < 4; ++mi) a2f[mi] = LDA(4+mi, 0); }
    PRIO1; MF16(a1f, b1f, 0); PRIO0;
    { _Pragma("unroll") for (int mi = 0; mi < 4; ++mi) a3f[mi] = LDA(4+mi, 1); }
    PRIO1; MF16(a2f, b0f, 4); PRIO0;
    PRIO1; MF16(a3f, b1f, 4); PRIO0;
  }

  // ---- fused epilogue: agg -> tanh -> dot W_out -> per-n-tile row partials ----
  const int b_blk = m0 >> 9;   // 256-row block lies within one batch
  float rb[4], wc[4], wo[4];
#pragma unroll
  for (int ni = 0; ni < 4; ++ni) {
    const int n = n0 + wn*64 + ni*16 + fr;
    rb[ni] = row_bias[b_blk*H_ + n];
    wc[ni] = Wcv[n];
    wo[ni] = Wout[n];
  }
#pragma unroll
  for (int mi = 0; mi < 8; ++mi) {
#pragma unroll
    for (int j = 0; j < 4; ++j) {
      const int mloc = wm*128 + mi*16 + fq*4 + j;   // C/D: row=(lane>>4)*4+reg
      const float pam = past_attn[m0 + mloc];
      float part = 0.f;
#pragma unroll
      for (int ni = 0; ni < 4; ++ni) {
        float agg = acc[mi][ni][j] + rb[ni] + pam * wc[ni];
        part += tanh_fast(agg) * wo[ni];
      }
#pragma unroll
      for (int off = 1; off < 16; off <<= 1) part += __shfl_xor(part, off);
      if (fr == 0) rowsum[mloc][wn] = part;
    }
  }
  __syncthreads();
  if (tid < 256)
    logits_part[(size_t)nt4 * M_ + m0 + tid] =
        (rowsum[tid][0] + rowsum[tid][1]) + (rowsum[tid][2] + rowsum[tid][3]);
#undef LDA
#undef LDB
#undef STG_ALL
#undef MF16
#undef BAR
#undef PRIO1
#undef PRIO0
#undef VM0
}

// ---------------------------------------------------------------------------
// K2 (fallback, R2 path): fp32 reg-staged fused GEMM — used if ws too small
// ---------------------------------------------------------------------------
#define BM 128
#define BN 128
#define LDK 40
__global__ __launch_bounds__(256, 2)
void fused_gemm_f32_kernel(const float* __restrict__ A,
                           const float* __restrict__ Bt,
                           const float* __restrict__ row_bias,
                           const float* __restrict__ past_attn,
                           const float* __restrict__ Wcv,
                           const float* __restrict__ Wout,
                           float* __restrict__ logits_part) {
  __shared__ __bf16 As[BM][LDK];
  __shared__ __bf16 Bs[BN][LDK];
  __shared__ float  rowsum[BM][2];

  const int bid  = blockIdx.x;
  const int tile = (bid & 7) * 256 + (bid >> 3);
  const int mt = tile >> 3, nt = tile & 7;
  const int m0 = mt * BM,  n0 = nt * BN;

  const int tid  = threadIdx.x;
  const int wave = tid >> 6, lane = tid & 63;
  const int wm = wave >> 1, wn = wave & 1;

  const int sr = tid >> 1, sh = tid & 1;
  const float* Arow = A  + (size_t)(m0 + sr) * H_ + sh*16;
  const float* Brow = Bt + (size_t)(n0 + sr) * H_ + sh*16;

  f32x4 acc[4][4] = {};

  for (int kt = 0; kt < H_ / 32; ++kt) {
    float4 a4[4], b4[4];
#pragma unroll
    for (int i = 0; i < 4; ++i) a4[i] = *(const float4*)&Arow[kt*32 + i*4];
#pragma unroll
    for (int i = 0; i < 4; ++i) b4[i] = *(const float4*)&Brow[kt*32 + i*4];

    __syncthreads();
#pragma unroll
    for (int i = 0; i < 4; ++i) {
      bf16x4 va, vb;
      va[0]=(__bf16)a4[i].x; va[1]=(__bf16)a4[i].y; va[2]=(__bf16)a4[i].z; va[3]=(__bf16)a4[i].w;
      vb[0]=(__bf16)b4[i].x; vb[1]=(__bf16)b4[i].y; vb[2]=(__bf16)b4[i].z; vb[3]=(__bf16)b4[i].w;
      *(bf16x4*)&As[sr][sh*16 + i*4] = va;
      *(bf16x4*)&Bs[sr][sh*16 + i*4] = vb;
    }
    __syncthreads();

    bf16x8 af[4], bf_[4];
#pragma unroll
    for (int i = 0; i < 4; ++i)
      af[i]  = *(const bf16x8*)&As[wm*64 + i*16 + (lane & 15)][(lane >> 4) * 8];
#pragma unroll
    for (int i = 0; i < 4; ++i)
      bf_[i] = *(const bf16x8*)&Bs[wn*64 + i*16 + (lane & 15)][(lane >> 4) * 8];
#pragma unroll
    for (int mi = 0; mi < 4; ++mi)
#pragma unroll
      for (int ni = 0; ni < 4; ++ni)
        acc[mi][ni] = __builtin_amdgcn_mfma_f32_16x16x32_bf16(af[mi], bf_[ni], acc[mi][ni], 0, 0, 0);
  }

  const int b_blk = m0 >> 9;
  float rb[4], wc[4], wo[4];
#pragma unroll
  for (int ni = 0; ni < 4; ++ni) {
    const int n = n0 + wn*64 + ni*16 + (lane & 15);
    rb[ni] = row_bias[b_blk*H_ + n];
    wc[ni] = Wcv[n];
    wo[ni] = Wout[n];
  }
#pragma unroll
  for (int mi = 0; mi < 4; ++mi) {
#pragma unroll
    for (int j = 0; j < 4; ++j) {
      const int mloc = wm*64 + mi*16 + (lane >> 4)*4 + j;
      const float pam = past_attn[m0 + mloc];
      float part = 0.f;
#pragma unroll
      for (int ni = 0; ni < 4; ++ni) {
        float agg = acc[mi][ni][j] + rb[ni] + pam * wc[ni];
        part += tanh_fast(agg) * wo[ni];
      }
#pragma unroll
      for (int off = 1; off < 16; off <<= 1) part += __shfl_xor(part, off);
      if ((lane & 15) == 0) rowsum[mloc][wn] = part;
    }
  }
  __syncthreads();
  if (tid < BM)
    logits_part[(size_t)nt * M_ + m0 + tid] = rowsum[tid][0] + rowsum[tid][1];
}

// ---------------------------------------------------------------------------
// K3: logits = sum of NP partials (fixed order), stable softmax over s
// ---------------------------------------------------------------------------
template <int NP>
__global__ void softmax_kernel(const float* __restrict__ lp,
                               float* __restrict__ attn) {
  const int b = blockIdx.x;
  const int tid = threadIdx.x;
  const int wave = tid >> 6, lane = tid & 63;
  __shared__ float smax[4], ssum[4];

  float v[2];
#pragma unroll
  for (int u = 0; u < 2; ++u) {
    const int s = tid + u*256;
    float t = 0.f;
#pragma unroll
    for (int p = 0; p < NP; ++p) t += lp[(size_t)p * M_ + b*S_ + s];
    v[u] = t;
  }
  float mx = fmaxf(v[0], v[1]);
#pragma unroll
  for (int off = 32; off; off >>= 1) mx = fmaxf(mx, __shfl_xor(mx, off));
  if (lane == 0) smax[wave] = mx;
  __syncthreads();
  mx = fmaxf(fmaxf(smax[0], smax[1]), fmaxf(smax[2], smax[3]));

  float e0 = __expf(v[0] - mx), e1 = __expf(v[1] - mx);
  float sm = e0 + e1;
#pragma unroll
  for (int off = 32; off; off >>= 1) sm += __shfl_xor(sm, off);
  if (lane == 0) ssum[wave] = sm;
  __syncthreads();
  const float inv = 1.0f / (ssum[0] + ssum[1] + ssum[2] + ssum[3]);
  attn[b*S_ + tid]       = e0 * inv;
  attn[b*S_ + tid + 256] = e1 * inv;
}

// ---------------------------------------------------------------------------
// K4 fast path: h_attn partials over s-chunks from bf16 enhy (deterministic)
// ---------------------------------------------------------------------------
__global__ void hattn_part_kernel(const __bf16* __restrict__ enhy_bf,
                                  const float* __restrict__ attn,
                                  float* __restrict__ hpart) {
  const int b = blockIdx.x, sc = blockIdx.y;
  const int tid = threadIdx.x;
  __shared__ float at[128];
  if (tid < 128) at[tid] = attn[b*S_ + sc*128 + tid];
  __syncthreads();

  const __bf16* base = enhy_bf + (size_t)(b*S_ + sc*128) * H_ + tid*4;
  float4 acc = {0.f, 0.f, 0.f, 0.f};
#pragma unroll 4
  for (int s = 0; s < 128; ++s) {
    bf16x4 v = *(const bf16x4*)(base + (size_t)s * H_);
    const float w = at[s];
    acc.x += w * (float)v[0];
    acc.y += w * (float)v[1];
    acc.z += w * (float)v[2];
    acc.w += w * (float)v[3];
  }
  *(float4*)&hpart[(size_t)(b*4 + sc) * H_ + tid*4] = acc;
}

__global__ void hattn_sum_kernel(const float* __restrict__ hpart,
                                 float* __restrict__ out_h) {
  const int b = blockIdx.x;
  const int h4 = threadIdx.x * 4;
  float4 s = {0.f, 0.f, 0.f, 0.f};
#pragma unroll
  for (int c = 0; c < 4; ++c) {
    float4 p = *(const float4*)&hpart[(size_t)(b*4 + c) * H_ + h4];
    s.x += p.x; s.y += p.y; s.z += p.z; s.w += p.w;
  }
  *(float4*)&out_h[b*H_ + h4] = s;
}

// K4 fallback (fp32 enhy)
__global__ void hattn_f32_kernel(const float* __restrict__ enhy,
                                 const float* __restrict__ attn,
                                 float* __restrict__ h_attn) {
  const int b = blockIdx.x;
  const int h = blockIdx.y * 256 + threadIdx.x;
  __shared__ float at[S_];
  for (int s = threadIdx.x; s < S_; s += 256) at[s] = attn[b*S_ + s];
  __syncthreads();

  const float* base = enhy + (size_t)b * S_ * H_ + h;
  float acc0 = 0.f, acc1 = 0.f;
#pragma unroll 4
  for (int s = 0; s < S_; s += 2) {
    acc0 += at[s]     * base[(size_t)s * H_];
    acc1 += at[s + 1] * base[(size_t)(s + 1) * H_];
  }
  h_attn[b*H_ + h] = acc0 + acc1;
}

// ---------------------------------------------------------------------------
extern "C" void kernel_launch(void* const* d_in, const int* in_sizes, int n_in,
                              void* d_out, int out_size, void* d_ws, size_t ws_size,
                              hipStream_t stream) {
  const float* last_dehy = (const float*)d_in[0];
  const float* enhy      = (const float*)d_in[1];
  const float* past_attn = (const float*)d_in[2];
  const float* hidden    = (const float*)d_in[3];
  const float* W_en      = (const float*)d_in[4];
  const float* b_en      = (const float*)d_in[5];
  const float* W_de      = (const float*)d_in[6];
  const float* b_de      = (const float*)d_in[7];
  const float* W_cv      = (const float*)d_in[8];
  const float* b_cv      = (const float*)d_in[9];
  const float* W_out     = (const float*)d_in[10];

  float* out_h    = (float*)d_out;         // [64][1024]
  float* out_attn = out_h + B_*H_;         // [64][512]
  float* out_hid  = out_attn + B_*S_;      // [64][512]

  // ws layout (fast path):
  //   row_bias    [64*1024]   f32
  //   logits_part [4*32768]   f32
  //   hpart       [64*4*1024] f32
  //   A_bf        [32768*1024] bf16
  //   W_bf        [1024*1024]  bf16
  float*  row_bias    = (float*)d_ws;
  float*  logits_part = row_bias + B_*H_;
  float*  hpart       = logits_part + 4*M_;
  __bf16* A_bf        = (__bf16*)(hpart + B_*4*H_);
  __bf16* W_bf        = A_bf + (size_t)M_*H_;
  const size_t need = (size_t)(B_*H_ + 4*M_ + B_*4*H_)*4
                    + ((size_t)M_*H_ + (size_t)H_*H_)*2;

  rowbias_kernel<<<dim3(B_, 16), 256, 0, stream>>>(last_dehy, W_de, b_en, b_de, b_cv, row_bias);

  if (ws_size >= need) {
    convert_bf16_kernel<<<2048, 256, 0, stream>>>(enhy, A_bf, M_*H_/8);
    convert_bf16_kernel<<<512, 256, 0, stream>>>(W_en, W_bf, H_*H_/8);
    gemmsb_kernel<<<(M_/256)*(H_/256), 512, 0, stream>>>(A_bf, W_bf, row_bias, past_attn,
                                                         W_cv, W_out, logits_part);
    softmax_kernel<4><<<B_, 256, 0, stream>>>(logits_part, out_attn);
    hattn_part_kernel<<<dim3(B_, 4), 256, 0, stream>>>(A_bf, out_attn, hpart);
    hattn_sum_kernel<<<B_, 256, 0, stream>>>(hpart, out_h);
  } else {
    fused_gemm_f32_kernel<<<(M_/BM)*(H_/BN), 256, 0, stream>>>(enhy, W_en, row_bias, past_attn,
                                                               W_cv, W_out, logits_part);
    softmax_kernel<8><<<B_, 256, 0, stream>>>(logits_part, out_attn);
    hattn_f32_kernel<<<dim3(B_, 4), 256, 0, stream>>>(enhy, out_attn, out_h);
  }

  hipMemcpyAsync(out_hid, hidden, (size_t)B_*S_*sizeof(float),
                 hipMemcpyDeviceToDevice, stream);
}

// Round 12
// 204.317 us; speedup vs baseline: 3.5452x; 3.5452x over previous
//
#include <hip/hip_runtime.h>
#include <stdint.h>

#define B_ 64
#define S_ 512
#define H_ 1024
#define M_ (B_*S_)   // 32768 rows of the big GEMM

typedef __bf16 bf16x8 __attribute__((ext_vector_type(8)));
typedef __bf16 bf16x4 __attribute__((ext_vector_type(4)));
typedef float  f32x4  __attribute__((ext_vector_type(4)));

typedef const __attribute__((address_space(1))) uint32_t glb_u32;
typedef __attribute__((address_space(3))) uint32_t lds_u32;

__device__ __forceinline__ float tanh_fast(float x) {
  float e = __expf(2.0f * x);
  return 1.0f - 2.0f * __builtin_amdgcn_rcpf(e + 1.0f);
}

// ---------------------------------------------------------------------------
// K0: fp32 -> bf16 streaming convert
// ---------------------------------------------------------------------------
__global__ void convert_bf16_kernel(const float* __restrict__ in,
                                    __bf16* __restrict__ out, int n8) {
  int i = blockIdx.x * 256 + threadIdx.x;
  const int stride = gridDim.x * 256;
  for (; i < n8; i += stride) {
    const float4 a = ((const float4*)in)[2*i];
    const float4 b = ((const float4*)in)[2*i+1];
    bf16x8 v;
    v[0]=(__bf16)a.x; v[1]=(__bf16)a.y; v[2]=(__bf16)a.z; v[3]=(__bf16)a.w;
    v[4]=(__bf16)b.x; v[5]=(__bf16)b.y; v[6]=(__bf16)b.z; v[7]=(__bf16)b.w;
    ((bf16x8*)out)[i] = v;
  }
}

// ---------------------------------------------------------------------------
// K1: row_bias[b][o] = last_dehy[b]·W_de[o] + b_de[o]+b_en[o]+b_cv[o]
// ---------------------------------------------------------------------------
__global__ void rowbias_kernel(const float* __restrict__ ldh,
                               const float* __restrict__ Wde,
                               const float* __restrict__ ben,
                               const float* __restrict__ bde,
                               const float* __restrict__ bcv,
                               float* __restrict__ row_bias) {
  const int b    = blockIdx.x;
  const int og   = blockIdx.y;
  const int wave = threadIdx.x >> 6;
  const int lane = threadIdx.x & 63;

  float4 l4[4];
#pragma unroll
  for (int i = 0; i < 4; ++i)
    l4[i] = *(const float4*)&ldh[b*H_ + i*256 + lane*4];

  for (int oi = 0; oi < 16; ++oi) {
    const int o = og*64 + wave*16 + oi;
    const float* wr = &Wde[(size_t)o * H_];
    float s = 0.f;
#pragma unroll
    for (int i = 0; i < 4; ++i) {
      float4 w4 = *(const float4*)&wr[i*256 + lane*4];
      s += w4.x*l4[i].x + w4.y*l4[i].y + w4.z*l4[i].z + w4.w*l4[i].w;
    }
#pragma unroll
    for (int off = 32; off; off >>= 1) s += __shfl_xor(s, off);
    if (lane == 0) row_bias[b*H_ + o] = s + bde[o] + ben[o] + bcv[o];
  }
}

// ---------------------------------------------------------------------------
// K2: 256x256 bf16 GEMM with quadrant-level one-ahead register pipeline.
// Memory scheme identical to R10 (verified: conflicts=0, absmax 9.8e-4):
// dbuf 128KB, linear gload_lds dest + inverse-swizzled global src + XOR reads.
// Per K-tile: stage(t+1)->buf^1 at top; 4 quadrants x 16 MFMA; frags for
// quadrant Q+1 are ds_read BEFORE MFMA(Q) (two alternating register sets),
// so each cluster's lgkm wait is covered by the previous cluster's MFMA.
// One VM0+BAR per tile (before Q3), gating t+1 visibility AND buffer reuse.
// ---------------------------------------------------------------------------
__global__ __launch_bounds__(512, 1)
void gemmpp_kernel(const __bf16* __restrict__ A,
                   const __bf16* __restrict__ Bt,
                   const float* __restrict__ row_bias,
                   const float* __restrict__ past_attn,
                   const float* __restrict__ Wcv,
                   const float* __restrict__ Wout,
                   float* __restrict__ logits_part) {
  __shared__ __bf16 L[2][4][8192];   // [buf][half][elems] 128 KB
  __shared__ float  rowsum[256][4];

  // XCD-bijective swizzle: 4 n-tiles of one m-tile adjacent on one XCD.
  const int bid  = blockIdx.x;               // 512 blocks, 512 % 8 == 0
  const int tile = (bid & 7) * 64 + (bid >> 3);
  const int mt = tile >> 2, nt4 = tile & 3;
  const int m0 = mt * 256, n0 = nt4 * 256;

  const int tid  = threadIdx.x;
  const int w    = tid >> 6, lane = tid & 63;
  const int wm   = w >> 2,   wn   = w & 3;
  const int fr   = lane & 15, fq = lane >> 4;

  // fragment-read addressing (row&7 == fr&7 for all regions):
  const int o0 = fr*128 + ((fq ^ (fr & 7)) * 16);
  const int o1 = fr*128 + (((4 + fq) ^ (fr & 7)) * 16);
  const char* a0p = (const char*)L + wm*16384;
  const char* b0p = (const char*)L + 32768 + (wn >> 1)*16384 + (wn & 1)*8192;

  // staging: per-lane global src (inverse-swizzled), wave-uniform LDS dst
  const int srow = w*8 + (lane >> 3);
  const int sc16 = (lane & 7) ^ ((lane >> 3) & 7);
  const __bf16* gA = A  + (size_t)(m0 + srow)*H_ + sc16*8;
  const __bf16* gB = Bt + (size_t)(n0 + srow)*H_ + sc16*8;
  const __bf16 *paA0 = gA, *paA1 = gA + (size_t)64*H_,
               *paA2 = gA + (size_t)128*H_, *paA3 = gA + (size_t)192*H_;
  const __bf16 *paB0 = gB, *paB1 = gB + (size_t)64*H_,
               *paB2 = gB + (size_t)128*H_, *paB3 = gB + (size_t)192*H_;
  char* ldsw = (char*)L + w*1024;

#define STG_ALL(TB) do { \
    __builtin_amdgcn_global_load_lds((glb_u32*)paA0, (lds_u32*)(ldsw + (TB)*65536        ), 16, 0, 0); \
    __builtin_amdgcn_global_load_lds((glb_u32*)paA1, (lds_u32*)(ldsw + (TB)*65536 +  8192), 16, 0, 0); \
    __builtin_amdgcn_global_load_lds((glb_u32*)paA2, (lds_u32*)(ldsw + (TB)*65536 + 16384), 16, 0, 0); \
    __builtin_amdgcn_global_load_lds((glb_u32*)paA3, (lds_u32*)(ldsw + (TB)*65536 + 24576), 16, 0, 0); \
    __builtin_amdgcn_global_load_lds((glb_u32*)paB0, (lds_u32*)(ldsw + (TB)*65536 + 32768), 16, 0, 0); \
    __builtin_amdgcn_global_load_lds((glb_u32*)paB1, (lds_u32*)(ldsw + (TB)*65536 + 40960), 16, 0, 0); \
    __builtin_amdgcn_global_load_lds((glb_u32*)paB2, (lds_u32*)(ldsw + (TB)*65536 + 49152), 16, 0, 0); \
    __builtin_amdgcn_global_load_lds((glb_u32*)paB3, (lds_u32*)(ldsw + (TB)*65536 + 57344), 16, 0, 0); \
    paA0 += 64; paA1 += 64; paA2 += 64; paA3 += 64;                                       \
    paB0 += 64; paB1 += 64; paB2 += 64; paB3 += 64; } while (0)

  f32x4 acc[8][4] = {};
  bf16x8 s0a[8], s0b[4], s1a[8], s1b[4];   // two frag sets (one-ahead pipe)

  // READ quadrant (MIB in {0,4}, NIB in {0,2}) from byte-offset BUFOFF into set S
#define READ_Q(Sa, Sb, MIB, NIB, BUFOFF) do {                                       \
    _Pragma("unroll") for (int mi = 0; mi < 4; ++mi)                                \
      _Pragma("unroll") for (int kk = 0; kk < 2; ++kk)                              \
        Sa[mi*2+kk] = *(const bf16x8*)(a0p + (BUFOFF) + (kk ? o1 : o0) + ((MIB)+mi)*2048); \
    _Pragma("unroll") for (int ni = 0; ni < 2; ++ni)                                \
      _Pragma("unroll") for (int kk = 0; kk < 2; ++kk)                              \
        Sb[ni*2+kk] = *(const bf16x8*)(b0p + (BUFOFF) + (kk ? o1 : o0) + ((NIB)+ni)*2048); \
  } while (0)

#define MF_Q(Sa, Sb, MIB, NIB) {                                                    \
    _Pragma("unroll") for (int mi = 0; mi < 4; ++mi)                                \
      _Pragma("unroll") for (int ni = 0; ni < 2; ++ni)                              \
        _Pragma("unroll") for (int kk = 0; kk < 2; ++kk)                            \
          acc[(MIB)+mi][(NIB)+ni] = __builtin_amdgcn_mfma_f32_16x16x32_bf16(        \
              Sa[mi*2+kk], Sb[ni*2+kk], acc[(MIB)+mi][(NIB)+ni], 0, 0, 0); }

#define BAR   __builtin_amdgcn_s_barrier()
#define PRIO1 __builtin_amdgcn_s_setprio(1)
#define PRIO0 __builtin_amdgcn_s_setprio(0)
#define VM0   asm volatile("s_waitcnt vmcnt(0)" ::: "memory")

  // TILE: entering with s0 = Q0(t) frags. BUF = t's buffer offset sel (0/1).
#define TILE(BUF, NBUF, DO_STG, DO_NEXT) do {                       \
    if (DO_STG) STG_ALL(NBUF);                                      \
    READ_Q(s1a, s1b, 0, 2, (BUF)*65536);      /* Q1 frags */        \
    PRIO1; MF_Q(s0a, s0b, 0, 0); PRIO0;       /* Q0 */              \
    READ_Q(s0a, s0b, 4, 0, (BUF)*65536);      /* Q2 frags */        \
    PRIO1; MF_Q(s1a, s1b, 0, 2); PRIO0;       /* Q1 */              \
    READ_Q(s1a, s1b, 4, 2, (BUF)*65536);      /* Q3 frags */        \
    PRIO1; MF_Q(s0a, s0b, 4, 0); PRIO0;       /* Q2 */              \
    VM0; BAR;                                 /* t+1 landed; t free */\
    if (DO_NEXT) READ_Q(s0a, s0b, 0, 0, (NBUF)*65536); /* Q0(t+1) */\
    PRIO1; MF_Q(s1a, s1b, 4, 2); PRIO0;       /* Q3 */              \
  } while (0)

  // prologue: stage tile 0 -> buf0, drain, read Q0(t0).
  STG_ALL(0);
  VM0;
  BAR;
  READ_Q(s0a, s0b, 0, 0, 0);

#pragma unroll 1
  for (int it = 0; it < 7; ++it) {    // t = 0..13
    TILE(0, 1, 1, 1);
    TILE(1, 0, 1, 1);
  }
  TILE(0, 1, 1, 1);                   // t = 14: stages t15 -> buf1
  TILE(1, 0, 0, 0);                   // t = 15

  // ---- fused epilogue: agg -> tanh -> dot W_out -> per-n-tile row partials ----
  const int b_blk = m0 >> 9;   // 256-row block lies within one batch
  float rb[4], wc[4], wo[4];
#pragma unroll
  for (int ni = 0; ni < 4; ++ni) {
    const int n = n0 + wn*64 + ni*16 + fr;
    rb[ni] = row_bias[b_blk*H_ + n];
    wc[ni] = Wcv[n];
    wo[ni] = Wout[n];
  }
#pragma unroll
  for (int mi = 0; mi < 8; ++mi) {
#pragma unroll
    for (int j = 0; j < 4; ++j) {
      const int mloc = wm*128 + mi*16 + fq*4 + j;   // C/D: row=(lane>>4)*4+reg
      const float pam = past_attn[m0 + mloc];
      float part = 0.f;
#pragma unroll
      for (int ni = 0; ni < 4; ++ni) {
        float agg = acc[mi][ni][j] + rb[ni] + pam * wc[ni];
        part += tanh_fast(agg) * wo[ni];
      }
#pragma unroll
      for (int off = 1; off < 16; off <<= 1) part += __shfl_xor(part, off);
      if (fr == 0) rowsum[mloc][wn] = part;
    }
  }
  __syncthreads();
  if (tid < 256)
    logits_part[(size_t)nt4 * M_ + m0 + tid] =
        (rowsum[tid][0] + rowsum[tid][1]) + (rowsum[tid][2] + rowsum[tid][3]);
#undef STG_ALL
#undef READ_Q
#undef MF_Q
#undef BAR
#undef PRIO1
#undef PRIO0
#undef VM0
#undef TILE
}

// ---------------------------------------------------------------------------
// K2 (fallback, R2 path): fp32 reg-staged fused GEMM — used if ws too small
// ---------------------------------------------------------------------------
#define BM 128
#define BN 128
#define LDK 40
__global__ __launch_bounds__(256, 2)
void fused_gemm_f32_kernel(const float* __restrict__ A,
                           const float* __restrict__ Bt,
                           const float* __restrict__ row_bias,
                           const float* __restrict__ past_attn,
                           const float* __restrict__ Wcv,
                           const float* __restrict__ Wout,
                           float* __restrict__ logits_part) {
  __shared__ __bf16 As[BM][LDK];
  __shared__ __bf16 Bs[BN][LDK];
  __shared__ float  rowsum[BM][2];

  const int bid  = blockIdx.x;
  const int tile = (bid & 7) * 256 + (bid >> 3);
  const int mt = tile >> 3, nt = tile & 7;
  const int m0 = mt * BM,  n0 = nt * BN;

  const int tid  = threadIdx.x;
  const int wave = tid >> 6, lane = tid & 63;
  const int wm = wave >> 1, wn = wave & 1;

  const int sr = tid >> 1, sh = tid & 1;
  const float* Arow = A  + (size_t)(m0 + sr) * H_ + sh*16;
  const float* Brow = Bt + (size_t)(n0 + sr) * H_ + sh*16;

  f32x4 acc[4][4] = {};

  for (int kt = 0; kt < H_ / 32; ++kt) {
    float4 a4[4], b4[4];
#pragma unroll
    for (int i = 0; i < 4; ++i) a4[i] = *(const float4*)&Arow[kt*32 + i*4];
#pragma unroll
    for (int i = 0; i < 4; ++i) b4[i] = *(const float4*)&Brow[kt*32 + i*4];

    __syncthreads();
#pragma unroll
    for (int i = 0; i < 4; ++i) {
      bf16x4 va, vb;
      va[0]=(__bf16)a4[i].x; va[1]=(__bf16)a4[i].y; va[2]=(__bf16)a4[i].z; va[3]=(__bf16)a4[i].w;
      vb[0]=(__bf16)b4[i].x; vb[1]=(__bf16)b4[i].y; vb[2]=(__bf16)b4[i].z; vb[3]=(__bf16)b4[i].w;
      *(bf16x4*)&As[sr][sh*16 + i*4] = va;
      *(bf16x4*)&Bs[sr][sh*16 + i*4] = vb;
    }
    __syncthreads();

    bf16x8 af[4], bf_[4];
#pragma unroll
    for (int i = 0; i < 4; ++i)
      af[i]  = *(const bf16x8*)&As[wm*64 + i*16 + (lane & 15)][(lane >> 4) * 8];
#pragma unroll
    for (int i = 0; i < 4; ++i)
      bf_[i] = *(const bf16x8*)&Bs[wn*64 + i*16 + (lane & 15)][(lane >> 4) * 8];
#pragma unroll
    for (int mi = 0; mi < 4; ++mi)
#pragma unroll
      for (int ni = 0; ni < 4; ++ni)
        acc[mi][ni] = __builtin_amdgcn_mfma_f32_16x16x32_bf16(af[mi], bf_[ni], acc[mi][ni], 0, 0, 0);
  }

  const int b_blk = m0 >> 9;
  float rb[4], wc[4], wo[4];
#pragma unroll
  for (int ni = 0; ni < 4; ++ni) {
    const int n = n0 + wn*64 + ni*16 + (lane & 15);
    rb[ni] = row_bias[b_blk*H_ + n];
    wc[ni] = Wcv[n];
    wo[ni] = Wout[n];
  }
#pragma unroll
  for (int mi = 0; mi < 4; ++mi) {
#pragma unroll
    for (int j = 0; j < 4; ++j) {
      const int mloc = wm*64 + mi*16 + (lane >> 4)*4 + j;
      const float pam = past_attn[m0 + mloc];
      float part = 0.f;
#pragma unroll
      for (int ni = 0; ni < 4; ++ni) {
        float agg = acc[mi][ni][j] + rb[ni] + pam * wc[ni];
        part += tanh_fast(agg) * wo[ni];
      }
#pragma unroll
      for (int off = 1; off < 16; off <<= 1) part += __shfl_xor(part, off);
      if ((lane & 15) == 0) rowsum[mloc][wn] = part;
    }
  }
  __syncthreads();
  if (tid < BM)
    logits_part[(size_t)nt * M_ + m0 + tid] = rowsum[tid][0] + rowsum[tid][1];
}

// ---------------------------------------------------------------------------
// K3: logits = sum of NP partials (fixed order), stable softmax over s
// ---------------------------------------------------------------------------
template <int NP>
__global__ void softmax_kernel(const float* __restrict__ lp,
                               float* __restrict__ attn) {
  const int b = blockIdx.x;
  const int tid = threadIdx.x;
  const int wave = tid >> 6, lane = tid & 63;
  __shared__ float smax[4], ssum[4];

  float v[2];
#pragma unroll
  for (int u = 0; u < 2; ++u) {
    const int s = tid + u*256;
    float t = 0.f;
#pragma unroll
    for (int p = 0; p < NP; ++p) t += lp[(size_t)p * M_ + b*S_ + s];
    v[u] = t;
  }
  float mx = fmaxf(v[0], v[1]);
#pragma unroll
  for (int off = 32; off; off >>= 1) mx = fmaxf(mx, __shfl_xor(mx, off));
  if (lane == 0) smax[wave] = mx;
  __syncthreads();
  mx = fmaxf(fmaxf(smax[0], smax[1]), fmaxf(smax[2], smax[3]));

  float e0 = __expf(v[0] - mx), e1 = __expf(v[1] - mx);
  float sm = e0 + e1;
#pragma unroll
  for (int off = 32; off; off >>= 1) sm += __shfl_xor(sm, off);
  if (lane == 0) ssum[wave] = sm;
  __syncthreads();
  const float inv = 1.0f / (ssum[0] + ssum[1] + ssum[2] + ssum[3]);
  attn[b*S_ + tid]       = e0 * inv;
  attn[b*S_ + tid + 256] = e1 * inv;
}

// ---------------------------------------------------------------------------
// K4 fast path: h_attn partials over s-chunks from bf16 enhy (deterministic)
// ---------------------------------------------------------------------------
__global__ void hattn_part_kernel(const __bf16* __restrict__ enhy_bf,
                                  const float* __restrict__ attn,
                                  float* __restrict__ hpart) {
  const int b = blockIdx.x, sc = blockIdx.y;
  const int tid = threadIdx.x;
  __shared__ float at[128];
  if (tid < 128) at[tid] = attn[b*S_ + sc*128 + tid];
  __syncthreads();

  const __bf16* base = enhy_bf + (size_t)(b*S_ + sc*128) * H_ + tid*4;
  float4 acc = {0.f, 0.f, 0.f, 0.f};
#pragma unroll 4
  for (int s = 0; s < 128; ++s) {
    bf16x4 v = *(const bf16x4*)(base + (size_t)s * H_);
    const float w = at[s];
    acc.x += w * (float)v[0];
    acc.y += w * (float)v[1];
    acc.z += w * (float)v[2];
    acc.w += w * (float)v[3];
  }
  *(float4*)&hpart[(size_t)(b*4 + sc) * H_ + tid*4] = acc;
}

__global__ void hattn_sum_kernel(const float* __restrict__ hpart,
                                 float* __restrict__ out_h) {
  const int b = blockIdx.x;
  const int h4 = threadIdx.x * 4;
  float4 s = {0.f, 0.f, 0.f, 0.f};
#pragma unroll
  for (int c = 0; c < 4; ++c) {
    float4 p = *(const float4*)&hpart[(size_t)(b*4 + c) * H_ + h4];
    s.x += p.x; s.y += p.y; s.z += p.z; s.w += p.w;
  }
  *(float4*)&out_h[b*H_ + h4] = s;
}

// K4 fallback (fp32 enhy)
__global__ void hattn_f32_kernel(const float* __restrict__ enhy,
                                 const float* __restrict__ attn,
                                 float* __restrict__ h_attn) {
  const int b = blockIdx.x;
  const int h = blockIdx.y * 256 + threadIdx.x;
  __shared__ float at[S_];
  for (int s = threadIdx.x; s < S_; s += 256) at[s] = attn[b*S_ + s];
  __syncthreads();

  const float* base = enhy + (size_t)b * S_ * H_ + h;
  float acc0 = 0.f, acc1 = 0.f;
#pragma unroll 4
  for (int s = 0; s < S_; s += 2) {
    acc0 += at[s]     * base[(size_t)s * H_];
    acc1 += at[s + 1] * base[(size_t)(s + 1) * H_];
  }
  h_attn[b*H_ + h] = acc0 + acc1;
}

// ---------------------------------------------------------------------------
extern "C" void kernel_launch(void* const* d_in, const int* in_sizes, int n_in,
                              void* d_out, int out_size, void* d_ws, size_t ws_size,
                              hipStream_t stream) {
  const float* last_dehy = (const float*)d_in[0];
  const float* enhy      = (const float*)d_in[1];
  const float* past_attn = (const float*)d_in[2];
  const float* hidden    = (const float*)d_in[3];
  const float* W_en      = (const float*)d_in[4];
  const float* b_en      = (const float*)d_in[5];
  const float* W_de      = (const float*)d_in[6];
  const float* b_de      = (const float*)d_in[7];
  const float* W_cv      = (const float*)d_in[8];
  const float* b_cv      = (const float*)d_in[9];
  const float* W_out     = (const float*)d_in[10];

  float* out_h    = (float*)d_out;         // [64][1024]
  float* out_attn = out_h + B_*H_;         // [64][512]
  float* out_hid  = out_attn + B_*S_;      // [64][512]

  // ws layout (fast path):
  //   row_bias    [64*1024]   f32
  //   logits_part [4*32768]   f32
  //   hpart       [64*4*1024] f32
  //   A_bf        [32768*1024] bf16
  //   W_bf        [1024*1024]  bf16
  float*  row_bias    = (float*)d_ws;
  float*  logits_part = row_bias + B_*H_;
  float*  hpart       = logits_part + 4*M_;
  __bf16* A_bf        = (__bf16*)(hpart + B_*4*H_);
  __bf16* W_bf        = A_bf + (size_t)M_*H_;
  const size_t need = (size_t)(B_*H_ + 4*M_ + B_*4*H_)*4
                    + ((size_t)M_*H_ + (size_t)H_*H_)*2;

  rowbias_kernel<<<dim3(B_, 16), 256, 0, stream>>>(last_dehy, W_de, b_en, b_de, b_cv, row_bias);

  if (ws_size >= need) {
    convert_bf16_kernel<<<2048, 256, 0, stream>>>(enhy, A_bf, M_*H_/8);
    convert_bf16_kernel<<<512, 256, 0, stream>>>(W_en, W_bf, H_*H_/8);
    gemmpp_kernel<<<(M_/256)*(H_/256), 512, 0, stream>>>(A_bf, W_bf, row_bias, past_attn,
                                                         W_cv, W_out, logits_part);
    softmax_kernel<4><<<B_, 256, 0, stream>>>(logits_part, out_attn);
    hattn_part_kernel<<<dim3(B_, 4), 256, 0, stream>>>(A_bf, out_attn, hpart);
    hattn_sum_kernel<<<B_, 256, 0, stream>>>(hpart, out_h);
  } else {
    fused_gemm_f32_kernel<<<(M_/BM)*(H_/BN), 256, 0, stream>>>(enhy, W_en, row_bias, past_attn,
                                                               W_cv, W_out, logits_part);
    softmax_kernel<8><<<B_, 256, 0, stream>>>(logits_part, out_attn);
    hattn_f32_kernel<<<dim3(B_, 4), 256, 0, stream>>>(enhy, out_attn, out_h);
  }

  hipMemcpyAsync(out_hid, hidden, (size_t)B_*S_*sizeof(float),
                 hipMemcpyDeviceToDevice, stream);
}

// Round 13
// 135.921 us; speedup vs baseline: 5.3291x; 1.5032x over previous
//
#include <hip/hip_runtime.h>
#include <stdint.h>

#define B_ 64
#define S_ 512
#define H_ 1024
#define M_ (B_*S_)   // 32768 rows of the big GEMM

typedef __bf16 bf16x8 __attribute__((ext_vector_type(8)));
typedef __bf16 bf16x4 __attribute__((ext_vector_type(4)));
typedef float  f32x4  __attribute__((ext_vector_type(4)));

typedef const __attribute__((address_space(1))) uint32_t glb_u32;
typedef __attribute__((address_space(3))) uint32_t lds_u32;

__device__ __forceinline__ float tanh_fast(float x) {
  float e = __expf(2.0f * x);
  return 1.0f - 2.0f * __builtin_amdgcn_rcpf(e + 1.0f);
}

// ---------------------------------------------------------------------------
// K0: fp32 -> bf16 streaming convert
// ---------------------------------------------------------------------------
__global__ void convert_bf16_kernel(const float* __restrict__ in,
                                    __bf16* __restrict__ out, int n8) {
  int i = blockIdx.x * 256 + threadIdx.x;
  const int stride = gridDim.x * 256;
  for (; i < n8; i += stride) {
    const float4 a = ((const float4*)in)[2*i];
    const float4 b = ((const float4*)in)[2*i+1];
    bf16x8 v;
    v[0]=(__bf16)a.x; v[1]=(__bf16)a.y; v[2]=(__bf16)a.z; v[3]=(__bf16)a.w;
    v[4]=(__bf16)b.x; v[5]=(__bf16)b.y; v[6]=(__bf16)b.z; v[7]=(__bf16)b.w;
    ((bf16x8*)out)[i] = v;
  }
}

// ---------------------------------------------------------------------------
// K1: row_bias[b][o] = last_dehy[b]·W_de[o] + b_de[o]+b_en[o]+b_cv[o]
// ---------------------------------------------------------------------------
__global__ void rowbias_kernel(const float* __restrict__ ldh,
                               const float* __restrict__ Wde,
                               const float* __restrict__ ben,
                               const float* __restrict__ bde,
                               const float* __restrict__ bcv,
                               float* __restrict__ row_bias) {
  const int b    = blockIdx.x;
  const int og   = blockIdx.y;
  const int wave = threadIdx.x >> 6;
  const int lane = threadIdx.x & 63;

  float4 l4[4];
#pragma unroll
  for (int i = 0; i < 4; ++i)
    l4[i] = *(const float4*)&ldh[b*H_ + i*256 + lane*4];

  for (int oi = 0; oi < 16; ++oi) {
    const int o = og*64 + wave*16 + oi;
    const float* wr = &Wde[(size_t)o * H_];
    float s = 0.f;
#pragma unroll
    for (int i = 0; i < 4; ++i) {
      float4 w4 = *(const float4*)&wr[i*256 + lane*4];
      s += w4.x*l4[i].x + w4.y*l4[i].y + w4.z*l4[i].z + w4.w*l4[i].w;
    }
#pragma unroll
    for (int off = 32; off; off >>= 1) s += __shfl_xor(s, off);
    if (lane == 0) row_bias[b*H_ + o] = s + bde[o] + ben[o] + bcv[o];
  }
}

// ---------------------------------------------------------------------------
// K2: 128x256 bf16 GEMM, single-buffer, 8 waves (wave tile 64x64, acc=64 VGPR)
// -> 2-3 blocks/CU for cross-block stall hiding. 48 KB LDS/tile, 87 FLOP per
// staged byte (1.33x the 128^2 tile). Verified memory scheme: linear
// gload_lds dest + inverse-swizzled global source + XOR'd ds_read
// (conflicts=0), __syncthreads-managed waits. Fused tanh/dot epilogue.
// ---------------------------------------------------------------------------
__global__ __launch_bounds__(512, 2)
void gemmw_kernel(const __bf16* __restrict__ A,
                  const __bf16* __restrict__ Bt,
                  const float* __restrict__ row_bias,
                  const float* __restrict__ past_attn,
                  const float* __restrict__ Wcv,
                  const float* __restrict__ Wout,
                  float* __restrict__ logits_part) {
  __shared__ __bf16 L[(128 + 256) * 64];   // A [0,16K) + B [16K,48K) bytes
  __shared__ float  rowsum[128][4];

  // XCD-bijective swizzle: 4 n-tiles of one m-stripe adjacent on one XCD.
  const int bid  = blockIdx.x;               // 1024 blocks, 1024 % 8 == 0
  const int tile = (bid & 7) * 128 + (bid >> 3);
  const int mt = tile >> 2, nt4 = tile & 3;
  const int m0 = mt * 128, n0 = nt4 * 256;

  const int tid  = threadIdx.x;
  const int w    = tid >> 6, lane = tid & 63;
  const int wm   = w >> 2,   wn   = w & 3;   // wm 0..1 (A 64-row half), wn 0..3 (B 64-col quarter)
  const int fr   = lane & 15, fq = lane >> 4;

  // fragment-read addressing (row&7 == fr&7 for all regions):
  const int o0 = fr*128 + ((fq ^ (fr & 7)) * 16);
  const int o1 = fr*128 + (((4 + fq) ^ (fr & 7)) * 16);
  const char* a0p = (const char*)L + wm*8192;
  const char* b0p = (const char*)L + 16384 + wn*8192;

  // staging: per-lane global src (inverse-swizzled), wave-uniform LDS dst
  const int srow = w*8 + (lane >> 3);
  const int sc16 = (lane & 7) ^ ((lane >> 3) & 7);
  const __bf16* gA = A  + (size_t)(m0 + srow)*H_ + sc16*8;
  const __bf16* gB = Bt + (size_t)(n0 + srow)*H_ + sc16*8;
  char* ldsw = (char*)L + w*1024;

  f32x4 acc[4][4] = {};   // 64 VGPR

#pragma unroll 1
  for (int kt = 0; kt < 16; ++kt) {
    // ---- stage this tile: A 2 rounds, B 4 rounds (6 gload_lds/thread) ----
#pragma unroll
    for (int r = 0; r < 2; ++r)
      __builtin_amdgcn_global_load_lds((glb_u32*)(gA + (size_t)(r*64)*H_),
                                       (lds_u32*)(ldsw + r*8192), 16, 0, 0);
#pragma unroll
    for (int r = 0; r < 4; ++r)
      __builtin_amdgcn_global_load_lds((glb_u32*)(gB + (size_t)(r*64)*H_),
                                       (lds_u32*)(ldsw + 16384 + r*8192), 16, 0, 0);
    gA += 64; gB += 64;
    __syncthreads();   // drains vmcnt+lgkm: tile resident

    // ---- compute: 2 kk-halves x 16 MFMA ----
#pragma unroll
    for (int kk = 0; kk < 2; ++kk) {
      bf16x8 af[4], bf[4];
      const int ok = kk ? o1 : o0;
#pragma unroll
      for (int mi = 0; mi < 4; ++mi) af[mi] = *(const bf16x8*)(a0p + ok + mi*2048);
#pragma unroll
      for (int ni = 0; ni < 4; ++ni) bf[ni] = *(const bf16x8*)(b0p + ok + ni*2048);
#pragma unroll
      for (int mi = 0; mi < 4; ++mi)
#pragma unroll
        for (int ni = 0; ni < 4; ++ni)
          acc[mi][ni] = __builtin_amdgcn_mfma_f32_16x16x32_bf16(af[mi], bf[ni], acc[mi][ni], 0, 0, 0);
    }
    __syncthreads();   // all waves done reading -> safe to overwrite next iter
  }

  // ---- fused epilogue: agg -> tanh -> dot W_out -> per-n-tile row partials ----
  const int b_blk = m0 >> 9;   // 128-row stripe lies within one batch (S_=512)
  float rb[4], wc[4], wo[4];
#pragma unroll
  for (int ni = 0; ni < 4; ++ni) {
    const int n = n0 + wn*64 + ni*16 + fr;
    rb[ni] = row_bias[b_blk*H_ + n];
    wc[ni] = Wcv[n];
    wo[ni] = Wout[n];
  }
#pragma unroll
  for (int mi = 0; mi < 4; ++mi) {
#pragma unroll
    for (int j = 0; j < 4; ++j) {
      const int mloc = wm*64 + mi*16 + fq*4 + j;   // C/D: row=(lane>>4)*4+reg
      const float pam = past_attn[m0 + mloc];
      float part = 0.f;
#pragma unroll
      for (int ni = 0; ni < 4; ++ni) {
        float agg = acc[mi][ni][j] + rb[ni] + pam * wc[ni];
        part += tanh_fast(agg) * wo[ni];
      }
#pragma unroll
      for (int off = 1; off < 16; off <<= 1) part += __shfl_xor(part, off);
      if (fr == 0) rowsum[mloc][wn] = part;
    }
  }
  __syncthreads();
  if (tid < 128)
    logits_part[(size_t)nt4 * M_ + m0 + tid] =
        (rowsum[tid][0] + rowsum[tid][1]) + (rowsum[tid][2] + rowsum[tid][3]);
}

// ---------------------------------------------------------------------------
// K2 (fallback, R2 path): fp32 reg-staged fused GEMM — used if ws too small
// ---------------------------------------------------------------------------
#define BM 128
#define BN 128
#define LDK 40
__global__ __launch_bounds__(256, 2)
void fused_gemm_f32_kernel(const float* __restrict__ A,
                           const float* __restrict__ Bt,
                           const float* __restrict__ row_bias,
                           const float* __restrict__ past_attn,
                           const float* __restrict__ Wcv,
                           const float* __restrict__ Wout,
                           float* __restrict__ logits_part) {
  __shared__ __bf16 As[BM][LDK];
  __shared__ __bf16 Bs[BN][LDK];
  __shared__ float  rowsum[BM][2];

  const int bid  = blockIdx.x;
  const int tile = (bid & 7) * 256 + (bid >> 3);
  const int mt = tile >> 3, nt = tile & 7;
  const int m0 = mt * BM,  n0 = nt * BN;

  const int tid  = threadIdx.x;
  const int wave = tid >> 6, lane = tid & 63;
  const int wm = wave >> 1, wn = wave & 1;

  const int sr = tid >> 1, sh = tid & 1;
  const float* Arow = A  + (size_t)(m0 + sr) * H_ + sh*16;
  const float* Brow = Bt + (size_t)(n0 + sr) * H_ + sh*16;

  f32x4 acc[4][4] = {};

  for (int kt = 0; kt < H_ / 32; ++kt) {
    float4 a4[4], b4[4];
#pragma unroll
    for (int i = 0; i < 4; ++i) a4[i] = *(const float4*)&Arow[kt*32 + i*4];
#pragma unroll
    for (int i = 0; i < 4; ++i) b4[i] = *(const float4*)&Brow[kt*32 + i*4];

    __syncthreads();
#pragma unroll
    for (int i = 0; i < 4; ++i) {
      bf16x4 va, vb;
      va[0]=(__bf16)a4[i].x; va[1]=(__bf16)a4[i].y; va[2]=(__bf16)a4[i].z; va[3]=(__bf16)a4[i].w;
      vb[0]=(__bf16)b4[i].x; vb[1]=(__bf16)b4[i].y; vb[2]=(__bf16)b4[i].z; vb[3]=(__bf16)b4[i].w;
      *(bf16x4*)&As[sr][sh*16 + i*4] = va;
      *(bf16x4*)&Bs[sr][sh*16 + i*4] = vb;
    }
    __syncthreads();

    bf16x8 af[4], bf_[4];
#pragma unroll
    for (int i = 0; i < 4; ++i)
      af[i]  = *(const bf16x8*)&As[wm*64 + i*16 + (lane & 15)][(lane >> 4) * 8];
#pragma unroll
    for (int i = 0; i < 4; ++i)
      bf_[i] = *(const bf16x8*)&Bs[wn*64 + i*16 + (lane & 15)][(lane >> 4) * 8];
#pragma unroll
    for (int mi = 0; mi < 4; ++mi)
#pragma unroll
      for (int ni = 0; ni < 4; ++ni)
        acc[mi][ni] = __builtin_amdgcn_mfma_f32_16x16x32_bf16(af[mi], bf_[ni], acc[mi][ni], 0, 0, 0);
  }

  const int b_blk = m0 >> 9;
  float rb[4], wc[4], wo[4];
#pragma unroll
  for (int ni = 0; ni < 4; ++ni) {
    const int n = n0 + wn*64 + ni*16 + (lane & 15);
    rb[ni] = row_bias[b_blk*H_ + n];
    wc[ni] = Wcv[n];
    wo[ni] = Wout[n];
  }
#pragma unroll
  for (int mi = 0; mi < 4; ++mi) {
#pragma unroll
    for (int j = 0; j < 4; ++j) {
      const int mloc = wm*64 + mi*16 + (lane >> 4)*4 + j;
      const float pam = past_attn[m0 + mloc];
      float part = 0.f;
#pragma unroll
      for (int ni = 0; ni < 4; ++ni) {
        float agg = acc[mi][ni][j] + rb[ni] + pam * wc[ni];
        part += tanh_fast(agg) * wo[ni];
      }
#pragma unroll
      for (int off = 1; off < 16; off <<= 1) part += __shfl_xor(part, off);
      if ((lane & 15) == 0) rowsum[mloc][wn] = part;
    }
  }
  __syncthreads();
  if (tid < BM)
    logits_part[(size_t)nt * M_ + m0 + tid] = rowsum[tid][0] + rowsum[tid][1];
}

// ---------------------------------------------------------------------------
// K3: logits = sum of NP partials (fixed order), stable softmax over s
// ---------------------------------------------------------------------------
template <int NP>
__global__ void softmax_kernel(const float* __restrict__ lp,
                               float* __restrict__ attn) {
  const int b = blockIdx.x;
  const int tid = threadIdx.x;
  const int wave = tid >> 6, lane = tid & 63;
  __shared__ float smax[4], ssum[4];

  float v[2];
#pragma unroll
  for (int u = 0; u < 2; ++u) {
    const int s = tid + u*256;
    float t = 0.f;
#pragma unroll
    for (int p = 0; p < NP; ++p) t += lp[(size_t)p * M_ + b*S_ + s];
    v[u] = t;
  }
  float mx = fmaxf(v[0], v[1]);
#pragma unroll
  for (int off = 32; off; off >>= 1) mx = fmaxf(mx, __shfl_xor(mx, off));
  if (lane == 0) smax[wave] = mx;
  __syncthreads();
  mx = fmaxf(fmaxf(smax[0], smax[1]), fmaxf(smax[2], smax[3]));

  float e0 = __expf(v[0] - mx), e1 = __expf(v[1] - mx);
  float sm = e0 + e1;
#pragma unroll
  for (int off = 32; off; off >>= 1) sm += __shfl_xor(sm, off);
  if (lane == 0) ssum[wave] = sm;
  __syncthreads();
  const float inv = 1.0f / (ssum[0] + ssum[1] + ssum[2] + ssum[3]);
  attn[b*S_ + tid]       = e0 * inv;
  attn[b*S_ + tid + 256] = e1 * inv;
}

// ---------------------------------------------------------------------------
// K4 fast path: h_attn partials over s-chunks from bf16 enhy (deterministic)
// ---------------------------------------------------------------------------
__global__ void hattn_part_kernel(const __bf16* __restrict__ enhy_bf,
                                  const float* __restrict__ attn,
                                  float* __restrict__ hpart) {
  const int b = blockIdx.x, sc = blockIdx.y;
  const int tid = threadIdx.x;
  __shared__ float at[128];
  if (tid < 128) at[tid] = attn[b*S_ + sc*128 + tid];
  __syncthreads();

  const __bf16* base = enhy_bf + (size_t)(b*S_ + sc*128) * H_ + tid*4;
  float4 acc = {0.f, 0.f, 0.f, 0.f};
#pragma unroll 4
  for (int s = 0; s < 128; ++s) {
    bf16x4 v = *(const bf16x4*)(base + (size_t)s * H_);
    const float w = at[s];
    acc.x += w * (float)v[0];
    acc.y += w * (float)v[1];
    acc.z += w * (float)v[2];
    acc.w += w * (float)v[3];
  }
  *(float4*)&hpart[(size_t)(b*4 + sc) * H_ + tid*4] = acc;
}

__global__ void hattn_sum_kernel(const float* __restrict__ hpart,
                                 float* __restrict__ out_h) {
  const int b = blockIdx.x;
  const int h4 = threadIdx.x * 4;
  float4 s = {0.f, 0.f, 0.f, 0.f};
#pragma unroll
  for (int c = 0; c < 4; ++c) {
    float4 p = *(const float4*)&hpart[(size_t)(b*4 + c) * H_ + h4];
    s.x += p.x; s.y += p.y; s.z += p.z; s.w += p.w;
  }
  *(float4*)&out_h[b*H_ + h4] = s;
}

// K4 fallback (fp32 enhy)
__global__ void hattn_f32_kernel(const float* __restrict__ enhy,
                                 const float* __restrict__ attn,
                                 float* __restrict__ h_attn) {
  const int b = blockIdx.x;
  const int h = blockIdx.y * 256 + threadIdx.x;
  __shared__ float at[S_];
  for (int s = threadIdx.x; s < S_; s += 256) at[s] = attn[b*S_ + s];
  __syncthreads();

  const float* base = enhy + (size_t)b * S_ * H_ + h;
  float acc0 = 0.f, acc1 = 0.f;
#pragma unroll 4
  for (int s = 0; s < S_; s += 2) {
    acc0 += at[s]     * base[(size_t)s * H_];
    acc1 += at[s + 1] * base[(size_t)(s + 1) * H_];
  }
  h_attn[b*H_ + h] = acc0 + acc1;
}

// ---------------------------------------------------------------------------
extern "C" void kernel_launch(void* const* d_in, const int* in_sizes, int n_in,
                              void* d_out, int out_size, void* d_ws, size_t ws_size,
                              hipStream_t stream) {
  const float* last_dehy = (const float*)d_in[0];
  const float* enhy      = (const float*)d_in[1];
  const float* past_attn = (const float*)d_in[2];
  const float* hidden    = (const float*)d_in[3];
  const float* W_en      = (const float*)d_in[4];
  const float* b_en      = (const float*)d_in[5];
  const float* W_de      = (const float*)d_in[6];
  const float* b_de      = (const float*)d_in[7];
  const float* W_cv      = (const float*)d_in[8];
  const float* b_cv      = (const float*)d_in[9];
  const float* W_out     = (const float*)d_in[10];

  float* out_h    = (float*)d_out;         // [64][1024]
  float* out_attn = out_h + B_*H_;         // [64][512]
  float* out_hid  = out_attn + B_*S_;      // [64][512]

  // ws layout (fast path):
  //   row_bias    [64*1024]   f32
  //   logits_part [4*32768]   f32
  //   hpart       [64*4*1024] f32
  //   A_bf        [32768*1024] bf16
  //   W_bf        [1024*1024]  bf16
  float*  row_bias    = (float*)d_ws;
  float*  logits_part = row_bias + B_*H_;
  float*  hpart       = logits_part + 4*M_;
  __bf16* A_bf        = (__bf16*)(hpart + B_*4*H_);
  __bf16* W_bf        = A_bf + (size_t)M_*H_;
  const size_t need = (size_t)(B_*H_ + 4*M_ + B_*4*H_)*4
                    + ((size_t)M_*H_ + (size_t)H_*H_)*2;

  rowbias_kernel<<<dim3(B_, 16), 256, 0, stream>>>(last_dehy, W_de, b_en, b_de, b_cv, row_bias);

  if (ws_size >= need) {
    convert_bf16_kernel<<<2048, 256, 0, stream>>>(enhy, A_bf, M_*H_/8);
    convert_bf16_kernel<<<512, 256, 0, stream>>>(W_en, W_bf, H_*H_/8);
    gemmw_kernel<<<(M_/128)*(H_/256), 512, 0, stream>>>(A_bf, W_bf, row_bias, past_attn,
                                                        W_cv, W_out, logits_part);
    softmax_kernel<4><<<B_, 256, 0, stream>>>(logits_part, out_attn);
    hattn_part_kernel<<<dim3(B_, 4), 256, 0, stream>>>(A_bf, out_attn, hpart);
    hattn_sum_kernel<<<B_, 256, 0, stream>>>(hpart, out_h);
  } else {
    fused_gemm_f32_kernel<<<(M_/BM)*(H_/BN), 256, 0, stream>>>(enhy, W_en, row_bias, past_attn,
                                                               W_cv, W_out, logits_part);
    softmax_kernel<8><<<B_, 256, 0, stream>>>(logits_part, out_attn);
    hattn_f32_kernel<<<dim3(B_, 4), 256, 0, stream>>>(enhy, out_attn, out_h);
  }

  hipMemcpyAsync(out_hid, hidden, (size_t)B_*S_*sizeof(float),
                 hipMemcpyDeviceToDevice, stream);
}